// Round 2
// baseline (6769.634 us; speedup 1.0000x reference)
//
#include <hip/hip_runtime.h>
#include <hip/hip_bf16.h>

#define HD    256
#define TENC  15
#define PLEN  45
#define MROW  32
#define NTHR  512
#define NBLK  (32768 / MROW)

typedef __attribute__((ext_vector_type(4))) float f32x4;
typedef __attribute__((ext_vector_type(8))) short bf16x8;

#define MFMA16 __builtin_amdgcn_mfma_f32_16x16x32_bf16

__device__ __forceinline__ unsigned short f2bf(float f) {
    union { float f; unsigned int u; } v; v.f = f;
    unsigned int r = v.u + 0x7FFF + ((v.u >> 16) & 1);  // RNE
    return (unsigned short)(r >> 16);
}

__global__ void cvt_bf16_kernel(const float* __restrict__ src,
                                unsigned short* __restrict__ dst, int n) {
    int i = blockIdx.x * blockDim.x + threadIdx.x;
    if (i < n) dst[i] = f2bf(src[i]);
}

// out_W padded to [16][256] bf16 (rows 4..15 zero)
__global__ void pad_outw_kernel(const float* __restrict__ src,
                                unsigned short* __restrict__ dst) {
    int i = blockIdx.x * blockDim.x + threadIdx.x;
    if (i < 16 * HD) dst[i] = (i < 4 * HD) ? f2bf(src[i]) : (unsigned short)0;
}

__global__ __launch_bounds__(NTHR, 4) void gru_main(
    const float* __restrict__ x,
    const float* __restrict__ eW, const float* __restrict__ eb,
    const unsigned short* __restrict__ encWih, const unsigned short* __restrict__ encWhh,
    const float* __restrict__ enc_bih, const float* __restrict__ enc_bhh,
    const unsigned short* __restrict__ decEW, const float* __restrict__ dec_eb,
    const unsigned short* __restrict__ decWih, const unsigned short* __restrict__ decWhh,
    const float* __restrict__ dec_bih, const float* __restrict__ dec_bhh,
    const unsigned short* __restrict__ outWp, const float* __restrict__ outb,
    float* __restrict__ out)
{
    __shared__ __align__(16) unsigned short ls_a[MROW * HD];  // 16KB, swizzled bf16
    __shared__ __align__(16) unsigned short ls_h[MROW * HD];  // 16KB, swizzled bf16
    __shared__ float ls_ew[HD * 4];
    __shared__ float ls_eb[HD];
    __shared__ float ls_bias[4 * HD];   // bR, bZ, bN(ih), bH(hh)
    __shared__ float ls_deb[HD];

    const int tid   = threadIdx.x;
    const int lane  = tid & 63;
    const int wv    = tid >> 6;       // 0..7
    const int cb    = wv * 32;        // wave's column base
    const int lrow  = lane & 15;
    const int kgrp  = lane >> 4;      // 0..3
    const int nbase = blockIdx.x * MROW;
    const int xr    = lrow & 7;       // swizzle key for A-frag rows

    for (int i = tid; i < HD * 4; i += NTHR) ls_ew[i] = eW[i];
    for (int i = tid; i < HD;     i += NTHR) ls_eb[i] = eb[i];
    if (tid < HD) {
        ls_bias[tid]          = enc_bih[tid] + enc_bhh[tid];
        ls_bias[HD + tid]     = enc_bih[HD + tid] + enc_bhh[HD + tid];
        ls_bias[2 * HD + tid] = enc_bih[2 * HD + tid];
        ls_bias[3 * HD + tid] = enc_bhh[2 * HD + tid];
    }

    // h carry fp32; C/D layout: row = rt*16 + kgrp*4 + r, col = cb + ct*16 + lrow
    f32x4 hreg[2][2];
    #pragma unroll
    for (int ct = 0; ct < 2; ++ct)
        #pragma unroll
        for (int rt = 0; rt < 2; ++rt)
            hreg[ct][rt] = f32x4{0.f, 0.f, 0.f, 0.f};

    f32x4 accR[2][2], accZ[2][2], accN1[2][2], accN2[2][2];

    auto zero_acc = [&]() {
        #pragma unroll
        for (int ct = 0; ct < 2; ++ct)
            #pragma unroll
            for (int rt = 0; rt < 2; ++rt) {
                accR[ct][rt]  = f32x4{0.f, 0.f, 0.f, 0.f};
                accZ[ct][rt]  = f32x4{0.f, 0.f, 0.f, 0.f};
                accN1[ct][rt] = f32x4{0.f, 0.f, 0.f, 0.f};
                accN2[ct][rt] = f32x4{0.f, 0.f, 0.f, 0.f};
            }
    };

    // acc{R,Z,T} += A(ls) @ W^T ; W is [768][256] bf16 row-major (r,z,n segments)
    auto gates_phase = [&](const unsigned short* __restrict__ ls,
                           const unsigned short* __restrict__ W,
                           f32x4 (&accT)[2][2]) {
        #pragma unroll 2
        for (int kk = 0; kk < 8; ++kk) {
            const int k  = kk * 32 + kgrp * 8;
            const int sh = ((kk * 4 + kgrp) ^ xr) << 4;
            bf16x8 a0 = *(const bf16x8*)((const char*)ls + lrow * 512 + sh);
            bf16x8 a1 = *(const bf16x8*)((const char*)ls + lrow * 512 + 8192 + sh);
            #pragma unroll
            for (int ct = 0; ct < 2; ++ct) {
                const unsigned short* w0 = W + (size_t)(cb + ct * 16 + lrow) * HD + k;
                bf16x8 br = *(const bf16x8*)(w0);
                bf16x8 bz = *(const bf16x8*)(w0 + 256 * HD);
                bf16x8 bn = *(const bf16x8*)(w0 + 512 * HD);
                accR[ct][0] = MFMA16(a0, br, accR[ct][0], 0, 0, 0);
                accR[ct][1] = MFMA16(a1, br, accR[ct][1], 0, 0, 0);
                accZ[ct][0] = MFMA16(a0, bz, accZ[ct][0], 0, 0, 0);
                accZ[ct][1] = MFMA16(a1, bz, accZ[ct][1], 0, 0, 0);
                accT[ct][0] = MFMA16(a0, bn, accT[ct][0], 0, 0, 0);
                accT[ct][1] = MFMA16(a1, bn, accT[ct][1], 0, 0, 0);
            }
        }
    };

    auto gru_update = [&]() {
        #pragma unroll
        for (int ct = 0; ct < 2; ++ct) {
            const int col = cb + ct * 16 + lrow;
            const float bR = ls_bias[col];
            const float bZ = ls_bias[HD + col];
            const float bN = ls_bias[2 * HD + col];
            const float bH = ls_bias[3 * HD + col];
            #pragma unroll
            for (int rt = 0; rt < 2; ++rt)
                #pragma unroll
                for (int r = 0; r < 4; ++r) {
                    float rr  = 1.f / (1.f + __expf(-(accR[ct][rt][r] + bR)));
                    float zz  = 1.f / (1.f + __expf(-(accZ[ct][rt][r] + bZ)));
                    float pre = accN1[ct][rt][r] + bN + rr * (accN2[ct][rt][r] + bH);
                    float nn  = 2.f / (1.f + __expf(-2.f * pre)) - 1.f;  // tanh
                    hreg[ct][rt][r] = (1.f - zz) * nn + zz * hreg[ct][rt][r];
                }
        }
    };

    auto write_h = [&]() {
        #pragma unroll
        for (int ct = 0; ct < 2; ++ct)
            #pragma unroll
            for (int rt = 0; rt < 2; ++rt)
                #pragma unroll
                for (int r = 0; r < 4; ++r) {
                    int row  = rt * 16 + kgrp * 4 + r;
                    int col  = cb + ct * 16 + lrow;
                    int addr = row * 512 + ((((col >> 3) ^ (row & 7)) << 4) | ((col & 7) << 1));
                    *(unsigned short*)((char*)ls_h + addr) = f2bf(hreg[ct][rt][r]);
                }
    };

    auto embed_step = [&](int t) {
        int row = tid & 31;
        int c0  = (tid >> 5) * 16;
        const float* xp = x + ((size_t)(nbase + row) * TENC + t) * 4;
        float x0 = xp[0], x1 = xp[1], x2 = xp[2], x3 = xp[3];
        #pragma unroll 4
        for (int j = 0; j < 16; ++j) {
            int col = c0 + j;
            const float* wp = &ls_ew[col * 4];
            float v = ls_eb[col] + x0 * wp[0] + x1 * wp[1] + x2 * wp[2] + x3 * wp[3];
            v = fmaxf(v, 0.f);
            int addr = row * 512 + ((((col >> 3) ^ (row & 7)) << 4) | ((col & 7) << 1));
            *(unsigned short*)((char*)ls_a + addr) = f2bf(v);
        }
    };

    // dec_in = relu(h @ dec_embed_W^T + dec_embed_b) -> ls_a
    auto dec_embed_phase = [&]() {
        f32x4 a2[2][2];
        #pragma unroll
        for (int ct = 0; ct < 2; ++ct)
            #pragma unroll
            for (int rt = 0; rt < 2; ++rt)
                a2[ct][rt] = f32x4{0.f, 0.f, 0.f, 0.f};
        #pragma unroll 2
        for (int kk = 0; kk < 8; ++kk) {
            const int k  = kk * 32 + kgrp * 8;
            const int sh = ((kk * 4 + kgrp) ^ xr) << 4;
            bf16x8 a0 = *(const bf16x8*)((const char*)ls_h + lrow * 512 + sh);
            bf16x8 a1 = *(const bf16x8*)((const char*)ls_h + lrow * 512 + 8192 + sh);
            #pragma unroll
            for (int ct = 0; ct < 2; ++ct) {
                bf16x8 b0 = *(const bf16x8*)(decEW + (size_t)(cb + ct * 16 + lrow) * HD + k);
                a2[ct][0] = MFMA16(a0, b0, a2[ct][0], 0, 0, 0);
                a2[ct][1] = MFMA16(a1, b0, a2[ct][1], 0, 0, 0);
            }
        }
        #pragma unroll
        for (int ct = 0; ct < 2; ++ct) {
            const int col = cb + ct * 16 + lrow;
            const float db = ls_deb[col];
            #pragma unroll
            for (int rt = 0; rt < 2; ++rt)
                #pragma unroll
                for (int r = 0; r < 4; ++r) {
                    int row  = rt * 16 + kgrp * 4 + r;
                    int addr = row * 512 + ((((col >> 3) ^ (row & 7)) << 4) | ((col & 7) << 1));
                    float v  = fmaxf(a2[ct][rt][r] + db, 0.f);
                    *(unsigned short*)((char*)ls_a + addr) = f2bf(v);
                }
        }
    };

    // out[row][0..3] = h[row] @ out_W^T + out_b via MFMA on waves 0,1
    auto out_layer = [&](int t) {
        if (wv < 2) {
            const int rt = wv;
            f32x4 o = f32x4{0.f, 0.f, 0.f, 0.f};
            #pragma unroll 2
            for (int kk = 0; kk < 8; ++kk) {
                const int k  = kk * 32 + kgrp * 8;
                const int sh = ((kk * 4 + kgrp) ^ xr) << 4;
                bf16x8 a = *(const bf16x8*)((const char*)ls_h + lrow * 512 + rt * 8192 + sh);
                bf16x8 b = *(const bf16x8*)(outWp + (size_t)lrow * HD + k);
                o = MFMA16(a, b, o, 0, 0, 0);
            }
            if (lrow < 4) {
                const float bo = outb[lrow];
                #pragma unroll
                for (int r = 0; r < 4; ++r) {
                    int row = rt * 16 + kgrp * 4 + r;
                    out[((size_t)(nbase + row) * PLEN + t) * 4 + lrow] = o[r] + bo;
                }
            }
        }
    };

    // ---- prologue ----
    __syncthreads();
    embed_step(0);
    write_h();               // h0 = 0
    __syncthreads();

    // ---- encoder ----
    for (int t = 0; t < TENC; ++t) {
        zero_acc();
        gates_phase(ls_a, encWih, accN1);
        gates_phase(ls_h, encWhh, accN2);
        gru_update();
        __syncthreads();
        write_h();
        if (t + 1 < TENC) embed_step(t + 1);
        __syncthreads();
    }

    // ---- decoder prologue ----
    if (tid < HD) {
        ls_bias[tid]          = dec_bih[tid] + dec_bhh[tid];
        ls_bias[HD + tid]     = dec_bih[HD + tid] + dec_bhh[HD + tid];
        ls_bias[2 * HD + tid] = dec_bih[2 * HD + tid];
        ls_bias[3 * HD + tid] = dec_bhh[2 * HD + tid];
        ls_deb[tid]           = dec_eb[tid];
    }
    __syncthreads();
    dec_embed_phase();       // dec_in0 from h_enc
    __syncthreads();

    // ---- decoder ----
    for (int t = 0; t < PLEN; ++t) {
        zero_acc();
        gates_phase(ls_a, decWih, accN1);
        gates_phase(ls_h, decWhh, accN2);
        gru_update();
        __syncthreads();
        write_h();
        __syncthreads();
        dec_embed_phase();
        out_layer(t);
        __syncthreads();
    }
}

extern "C" void kernel_launch(void* const* d_in, const int* in_sizes, int n_in,
                              void* d_out, int out_size, void* d_ws, size_t ws_size,
                              hipStream_t stream) {
    const float* x       = (const float*)d_in[0];
    const float* eW      = (const float*)d_in[1];
    const float* eb      = (const float*)d_in[2];
    const float* encWih  = (const float*)d_in[3];
    const float* encWhh  = (const float*)d_in[4];
    const float* enc_bih = (const float*)d_in[5];
    const float* enc_bhh = (const float*)d_in[6];
    const float* decEWf  = (const float*)d_in[7];
    const float* dec_eb  = (const float*)d_in[8];
    const float* decWihf = (const float*)d_in[9];
    const float* decWhhf = (const float*)d_in[10];
    const float* dec_bih = (const float*)d_in[11];
    const float* dec_bhh = (const float*)d_in[12];
    const float* outW    = (const float*)d_in[13];
    const float* outb    = (const float*)d_in[14];

    unsigned short* ws = (unsigned short*)d_ws;
    unsigned short* bWih_e = ws;                  // 3*H*H each
    unsigned short* bWhh_e = ws + 196608;
    unsigned short* bWih_d = ws + 2 * 196608;
    unsigned short* bWhh_d = ws + 3 * 196608;
    unsigned short* bEW_d  = ws + 4 * 196608;     // H*H
    unsigned short* bOWp   = ws + 4 * 196608 + 65536;  // 16*H

    const int n1 = 3 * HD * HD;
    const int n2 = HD * HD;
    cvt_bf16_kernel<<<(n1 + 255) / 256, 256, 0, stream>>>(encWih,  bWih_e, n1);
    cvt_bf16_kernel<<<(n1 + 255) / 256, 256, 0, stream>>>(encWhh,  bWhh_e, n1);
    cvt_bf16_kernel<<<(n1 + 255) / 256, 256, 0, stream>>>(decWihf, bWih_d, n1);
    cvt_bf16_kernel<<<(n1 + 255) / 256, 256, 0, stream>>>(decWhhf, bWhh_d, n1);
    cvt_bf16_kernel<<<(n2 + 255) / 256, 256, 0, stream>>>(decEWf,  bEW_d,  n2);
    pad_outw_kernel<<<(16 * HD + 255) / 256, 256, 0, stream>>>(outW, bOWp);

    gru_main<<<NBLK, NTHR, 0, stream>>>(
        x, eW, eb, bWih_e, bWhh_e, enc_bih, enc_bhh,
        bEW_d, dec_eb, bWih_d, bWhh_d, dec_bih, dec_bhh,
        bOWp, outb, (float*)d_out);
}

// Round 4
// 4161.258 us; speedup vs baseline: 1.6268x; 1.6268x over previous
//
#include <hip/hip_runtime.h>
#include <hip/hip_bf16.h>
#include <hip/hip_fp16.h>

#define HD    256
#define TENC  15
#define PLEN  45
#define MROW  128
#define NTHR  1024
#define NBLK  (32768 / MROW)   // 256 blocks = 1 per CU

typedef __attribute__((ext_vector_type(4))) float f32x4;
typedef __attribute__((ext_vector_type(8))) short bf16x8;

#define MFMA16 __builtin_amdgcn_mfma_f32_16x16x32_bf16

__device__ __forceinline__ unsigned short f2bf(float f) {
    union { float f; unsigned int u; } v; v.f = f;
    unsigned int r = v.u + 0x7FFF + ((v.u >> 16) & 1);  // RNE
    return (unsigned short)(r >> 16);
}

__global__ void cvt_bf16_kernel(const float* __restrict__ src,
                                unsigned short* __restrict__ dst, int n) {
    int i = blockIdx.x * blockDim.x + threadIdx.x;
    if (i < n) dst[i] = f2bf(src[i]);
}

// out_W padded to [16][256] bf16 (rows 4..15 zero)
__global__ void pad_outw_kernel(const float* __restrict__ src,
                                unsigned short* __restrict__ dst) {
    int i = blockIdx.x * blockDim.x + threadIdx.x;
    if (i < 16 * HD) dst[i] = (i < 4 * HD) ? f2bf(src[i]) : (unsigned short)0;
}

// Swizzled byte offset into a [MROW][HD] bf16 LDS tile (row stride 512B).
__device__ __forceinline__ int swz(int row, int col) {
    return row * 512 + ((((col >> 3) ^ (row & 7)) << 4) | ((col & 7) << 1));
}

__global__ __launch_bounds__(NTHR, 4) void gru_main(
    const float* __restrict__ x,
    const float* __restrict__ eW, const float* __restrict__ eb,
    const unsigned short* __restrict__ encWih, const unsigned short* __restrict__ encWhh,
    const float* __restrict__ enc_bih, const float* __restrict__ enc_bhh,
    const unsigned short* __restrict__ decEW, const float* __restrict__ dec_eb,
    const unsigned short* __restrict__ decWih, const unsigned short* __restrict__ decWhh,
    const float* __restrict__ dec_bih, const float* __restrict__ dec_bhh,
    const unsigned short* __restrict__ outWp, const float* __restrict__ outb,
    float* __restrict__ out)
{
    __shared__ __align__(16) unsigned short ls_a[MROW * HD];  // 64KB swizzled bf16
    __shared__ __align__(16) unsigned short ls_h[MROW * HD];  // 64KB swizzled bf16
    __shared__ float ls_ew[HD * 4];
    __shared__ float ls_eb[HD];
    __shared__ float ls_bias[4 * HD];   // bR, bZ, bN(ih), bH(hh)
    __shared__ float ls_deb[HD];

    const int tid   = threadIdx.x;
    const int lane  = tid & 63;
    const int wv    = tid >> 6;      // 0..15
    const int cb    = wv * 16;       // wave's 16 output columns
    const int lrow  = lane & 15;
    const int kgrp  = lane >> 4;     // 0..3
    const int xr    = lrow & 7;
    const int nbase = blockIdx.x * MROW;

    for (int i = tid; i < HD * 4; i += NTHR) ls_ew[i] = eW[i];
    if (tid < HD) {
        ls_eb[tid]            = eb[tid];
        ls_bias[tid]          = enc_bih[tid] + enc_bhh[tid];
        ls_bias[HD + tid]     = enc_bih[HD + tid] + enc_bhh[HD + tid];
        ls_bias[2 * HD + tid] = enc_bih[2 * HD + tid];
        ls_bias[3 * HD + tid] = enc_bhh[2 * HD + tid];
    }
    for (int i = tid; i < MROW * HD / 2; i += NTHR) ((unsigned int*)ls_h)[i] = 0u;

    // h carried as packed fp16 pairs: 16 VGPRs for 32 values. |h|<=1 always.
    __half2 hpk[8][2];
    #pragma unroll
    for (int i = 0; i < 8; ++i) {
        hpk[i][0] = __floats2half2_rn(0.f, 0.f);
        hpk[i][1] = __floats2half2_rn(0.f, 0.f);
    }

    f32x4 accR[4], accZ[4], accN1[4], accN2[4];

    auto zero_acc = [&]() {
        #pragma unroll
        for (int rt = 0; rt < 4; ++rt) {
            accR[rt]  = f32x4{0.f, 0.f, 0.f, 0.f};
            accZ[rt]  = f32x4{0.f, 0.f, 0.f, 0.f};
            accN1[rt] = f32x4{0.f, 0.f, 0.f, 0.f};
            accN2[rt] = f32x4{0.f, 0.f, 0.f, 0.f};
        }
    };

    // acc{R,Z,T} += A(ls rows rh*64..rh*64+63) @ W^T  (wave's 16 cols)
    auto gates_phase = [&](const unsigned short* __restrict__ ls, int rh,
                           const unsigned short* __restrict__ W,
                           f32x4 (&accT)[4]) {
        const char* ab = (const char*)ls + (size_t)(rh * 64 + lrow) * 512;
        const unsigned short* w0 = W + (size_t)(cb + lrow) * HD + kgrp * 8;
        #pragma unroll 2
        for (int kk = 0; kk < 8; ++kk) {
            const int sh = ((kk * 4 + kgrp) ^ xr) << 4;
            bf16x8 a0 = *(const bf16x8*)(ab + sh);
            bf16x8 a1 = *(const bf16x8*)(ab + sh + 8192);
            bf16x8 a2 = *(const bf16x8*)(ab + sh + 16384);
            bf16x8 a3 = *(const bf16x8*)(ab + sh + 24576);
            const unsigned short* wk = w0 + kk * 32;
            bf16x8 br = *(const bf16x8*)(wk);
            bf16x8 bz = *(const bf16x8*)(wk + 256 * HD);
            bf16x8 bn = *(const bf16x8*)(wk + 512 * HD);
            accR[0] = MFMA16(a0, br, accR[0], 0, 0, 0);
            accZ[0] = MFMA16(a0, bz, accZ[0], 0, 0, 0);
            accT[0] = MFMA16(a0, bn, accT[0], 0, 0, 0);
            accR[1] = MFMA16(a1, br, accR[1], 0, 0, 0);
            accZ[1] = MFMA16(a1, bz, accZ[1], 0, 0, 0);
            accT[1] = MFMA16(a1, bn, accT[1], 0, 0, 0);
            accR[2] = MFMA16(a2, br, accR[2], 0, 0, 0);
            accZ[2] = MFMA16(a2, bz, accZ[2], 0, 0, 0);
            accT[2] = MFMA16(a2, bn, accT[2], 0, 0, 0);
            accR[3] = MFMA16(a3, br, accR[3], 0, 0, 0);
            accZ[3] = MFMA16(a3, bz, accZ[3], 0, 0, 0);
            accT[3] = MFMA16(a3, bn, accT[3], 0, 0, 0);
        }
    };

    auto gru_update = [&](int rh) {
        const int col  = cb + lrow;
        const float bR = ls_bias[col];
        const float bZ = ls_bias[HD + col];
        const float bN = ls_bias[2 * HD + col];
        const float bH = ls_bias[3 * HD + col];
        #pragma unroll
        for (int rt = 0; rt < 4; ++rt) {
            #pragma unroll
            for (int p = 0; p < 2; ++p) {
                float2 hv = __half22float2(hpk[rh * 4 + rt][p]);
                float hn[2];
                #pragma unroll
                for (int q = 0; q < 2; ++q) {
                    int r = p * 2 + q;
                    float rr  = 1.f / (1.f + __expf(-(accR[rt][r] + bR)));
                    float zz  = 1.f / (1.f + __expf(-(accZ[rt][r] + bZ)));
                    float pre = accN1[rt][r] + bN + rr * (accN2[rt][r] + bH);
                    float nn  = 2.f / (1.f + __expf(-2.f * pre)) - 1.f;  // tanh
                    float ho  = (q == 0) ? hv.x : hv.y;
                    hn[q] = (1.f - zz) * nn + zz * ho;
                }
                hpk[rh * 4 + rt][p] = __floats2half2_rn(hn[0], hn[1]);
            }
        }
    };

    auto write_h = [&](int rh) {
        const int col = cb + lrow;
        #pragma unroll
        for (int rt = 0; rt < 4; ++rt)
            #pragma unroll
            for (int p = 0; p < 2; ++p) {
                float2 hv = __half22float2(hpk[rh * 4 + rt][p]);
                int row = rh * 64 + rt * 16 + kgrp * 4 + p * 2;
                *(unsigned short*)((char*)ls_h + swz(row, col))     = f2bf(hv.x);
                *(unsigned short*)((char*)ls_h + swz(row + 1, col)) = f2bf(hv.y);
            }
    };

    auto embed_step = [&](int rh, int t) {
        int row = rh * 64 + (tid & 63);
        int c0  = (tid >> 6) * 16;
        const float4 xv = *(const float4*)(x + ((size_t)(nbase + row) * TENC + t) * 4);
        #pragma unroll 4
        for (int j = 0; j < 16; ++j) {
            int col = c0 + j;
            const float* wp = &ls_ew[col * 4];
            float v = fmaf(xv.x, wp[0], fmaf(xv.y, wp[1],
                      fmaf(xv.z, wp[2], fmaf(xv.w, wp[3], ls_eb[col]))));
            v = fmaxf(v, 0.f);
            *(unsigned short*)((char*)ls_a + swz(row, col)) = f2bf(v);
        }
    };

    // dec_in(rows rh) = relu(h(rows rh) @ dec_embed_W^T + deb) -> ls_a
    auto dec_embed_phase = [&](int rh) {
        f32x4 a2[4];
        #pragma unroll
        for (int rt = 0; rt < 4; ++rt) a2[rt] = f32x4{0.f, 0.f, 0.f, 0.f};
        const char* ab = (const char*)ls_h + (size_t)(rh * 64 + lrow) * 512;
        const unsigned short* w0 = decEW + (size_t)(cb + lrow) * HD + kgrp * 8;
        #pragma unroll 2
        for (int kk = 0; kk < 8; ++kk) {
            const int sh = ((kk * 4 + kgrp) ^ xr) << 4;
            bf16x8 a0 = *(const bf16x8*)(ab + sh);
            bf16x8 a1 = *(const bf16x8*)(ab + sh + 8192);
            bf16x8 a2f = *(const bf16x8*)(ab + sh + 16384);
            bf16x8 a3 = *(const bf16x8*)(ab + sh + 24576);
            bf16x8 b0 = *(const bf16x8*)(w0 + kk * 32);
            a2[0] = MFMA16(a0,  b0, a2[0], 0, 0, 0);
            a2[1] = MFMA16(a1,  b0, a2[1], 0, 0, 0);
            a2[2] = MFMA16(a2f, b0, a2[2], 0, 0, 0);
            a2[3] = MFMA16(a3,  b0, a2[3], 0, 0, 0);
        }
        const int col  = cb + lrow;
        const float db = ls_deb[col];
        #pragma unroll
        for (int rt = 0; rt < 4; ++rt)
            #pragma unroll
            for (int r = 0; r < 4; ++r) {
                int row = rh * 64 + rt * 16 + kgrp * 4 + r;
                float v = fmaxf(a2[rt][r] + db, 0.f);
                *(unsigned short*)((char*)ls_a + swz(row, col)) = f2bf(v);
            }
    };

    // out rows of half rh via MFMA on waves 0..3 (wave wv -> row tile rh*64+wv*16)
    auto out_layer = [&](int rh, int t) {
        if (wv < 4) {
            const char* ab = (const char*)ls_h + (size_t)(rh * 64 + wv * 16 + lrow) * 512;
            const unsigned short* w0 = outWp + (size_t)lrow * HD + kgrp * 8;
            f32x4 o = f32x4{0.f, 0.f, 0.f, 0.f};
            #pragma unroll 2
            for (int kk = 0; kk < 8; ++kk) {
                const int sh = ((kk * 4 + kgrp) ^ xr) << 4;
                bf16x8 a = *(const bf16x8*)(ab + sh);
                bf16x8 b = *(const bf16x8*)(w0 + kk * 32);
                o = MFMA16(a, b, o, 0, 0, 0);
            }
            if (lrow < 4) {
                const float bo = outb[lrow];
                #pragma unroll
                for (int r = 0; r < 4; ++r) {
                    int row = rh * 64 + wv * 16 + kgrp * 4 + r;
                    out[((size_t)(nbase + row) * PLEN + t) * 4 + lrow] = o[r] + bo;
                }
            }
        }
    };

    // ---- prologue ----
    __syncthreads();             // ls_ew/ls_eb/bias staged, ls_h zeroed
    embed_step(0, 0);
    embed_step(1, 0);
    __syncthreads();             // ls_a ready

    // ---- encoder: 2 barriers/step ----
    for (int t = 0; t < TENC; ++t) {
        zero_acc();
        gates_phase(ls_a, 0, encWih, accN1);
        gates_phase(ls_h, 0, encWhh, accN2);
        gru_update(0);
        __syncthreads();                     // all reads of rows 0-63 done
        write_h(0);
        if (t + 1 < TENC) embed_step(0, t + 1);
        zero_acc();
        gates_phase(ls_a, 1, encWih, accN1);
        gates_phase(ls_h, 1, encWhh, accN2);
        gru_update(1);
        __syncthreads();                     // all reads of rows 64-127 done
        write_h(1);
        if (t + 1 < TENC) embed_step(1, t + 1);
    }

    // ---- encoder -> decoder transition ----
    __syncthreads();                         // write_h(1) visible
    if (tid < HD) {
        ls_bias[tid]          = dec_bih[tid] + dec_bhh[tid];
        ls_bias[HD + tid]     = dec_bih[HD + tid] + dec_bhh[HD + tid];
        ls_bias[2 * HD + tid] = dec_bih[2 * HD + tid];
        ls_bias[3 * HD + tid] = dec_bhh[2 * HD + tid];
        ls_deb[tid]           = dec_eb[tid];
    }
    __syncthreads();
    dec_embed_phase(0);                      // dec_in0 rows 0-63
    __syncthreads();
    dec_embed_phase(1);                      // dec_in0 rows 64-127

    // ---- decoder: 3 barriers/step ----
    for (int t = 0; t < PLEN; ++t) {
        zero_acc();
        gates_phase(ls_a, 0, decWih, accN1);
        gates_phase(ls_h, 0, decWhh, accN2);
        gru_update(0);
        __syncthreads();                     // B1
        write_h(0);
        zero_acc();
        gates_phase(ls_a, 1, decWih, accN1);
        gates_phase(ls_h, 1, decWhh, accN2);
        gru_update(1);
        __syncthreads();                     // B2
        write_h(1);
        dec_embed_phase(0);                  // next dec_in rows 0-63 (h(t) rows 0-63)
        out_layer(0, t);
        __syncthreads();                     // B3
        dec_embed_phase(1);                  // next dec_in rows 64-127
        out_layer(1, t);
    }
}

extern "C" void kernel_launch(void* const* d_in, const int* in_sizes, int n_in,
                              void* d_out, int out_size, void* d_ws, size_t ws_size,
                              hipStream_t stream) {
    const float* x       = (const float*)d_in[0];
    const float* eW      = (const float*)d_in[1];
    const float* eb      = (const float*)d_in[2];
    const float* encWih  = (const float*)d_in[3];
    const float* encWhh  = (const float*)d_in[4];
    const float* enc_bih = (const float*)d_in[5];
    const float* enc_bhh = (const float*)d_in[6];
    const float* decEWf  = (const float*)d_in[7];
    const float* dec_eb  = (const float*)d_in[8];
    const float* decWihf = (const float*)d_in[9];
    const float* decWhhf = (const float*)d_in[10];
    const float* dec_bih = (const float*)d_in[11];
    const float* dec_bhh = (const float*)d_in[12];
    const float* outW    = (const float*)d_in[13];
    const float* outb    = (const float*)d_in[14];

    unsigned short* ws = (unsigned short*)d_ws;
    unsigned short* bWih_e = ws;                  // 3*H*H each
    unsigned short* bWhh_e = ws + 196608;
    unsigned short* bWih_d = ws + 2 * 196608;
    unsigned short* bWhh_d = ws + 3 * 196608;
    unsigned short* bEW_d  = ws + 4 * 196608;     // H*H
    unsigned short* bOWp   = ws + 4 * 196608 + 65536;  // 16*H

    const int n1 = 3 * HD * HD;
    const int n2 = HD * HD;
    cvt_bf16_kernel<<<(n1 + 255) / 256, 256, 0, stream>>>(encWih,  bWih_e, n1);
    cvt_bf16_kernel<<<(n1 + 255) / 256, 256, 0, stream>>>(encWhh,  bWhh_e, n1);
    cvt_bf16_kernel<<<(n1 + 255) / 256, 256, 0, stream>>>(decWihf, bWih_d, n1);
    cvt_bf16_kernel<<<(n1 + 255) / 256, 256, 0, stream>>>(decWhhf, bWhh_d, n1);
    cvt_bf16_kernel<<<(n2 + 255) / 256, 256, 0, stream>>>(decEWf,  bEW_d,  n2);
    pad_outw_kernel<<<(16 * HD + 255) / 256, 256, 0, stream>>>(outW, bOWp);

    gru_main<<<NBLK, NTHR, 0, stream>>>(
        x, eW, eb, bWih_e, bWhh_e, enc_bih, enc_bhh,
        bEW_d, dec_eb, bWih_d, bWhh_d, dec_bih, dec_bhh,
        bOWp, outb, (float*)d_out);
}